// Round 11
// baseline (26.465 us; speedup 1.0000x reference)
//
#include <hip/hip_runtime.h>

#define NB 8
#define NQ 4096   // h*w
#define NP 2048
#define FINF 3.402823466e38f

typedef float f2 __attribute__((ext_vector_type(2)));
typedef float f4 __attribute__((ext_vector_type(4)));

// VOP3P packed FMA: ALL operands are 64-bit register pairs. Session lessons:
// no scalar src0 (R5); no op_sel packing / VGPR caps (R6/R7: allocator remat);
// no threadfence / release atomics for fusion (R8/R9: L2-writeback storm);
// do NOT shrink tiles for occupancy (R10: per-block fixed costs dominate).
__device__ __forceinline__ f2 pk_fma(f2 a, f2 b, f2 c) {
    f2 d;
    asm("v_pk_fma_f32 %0, %1, %2, %3" : "=v"(d) : "v"(a), "v"(b), "v"(c));
    return d;
}
__device__ __forceinline__ float min3f(float a, float b, float c) {
    float d;
    asm("v_min3_f32 %0, %1, %2, %3" : "=v"(d) : "v"(a), "v"(b), "v"(c));
    return d;
}

// Main: 512 blocks x 512 threads. R4's exact tiling (best measured: 20.45us total),
// but 2x threads per block: per-thread inner work halves, occupancy doubles to
// 16 waves/CU (4/SIMD) at 68KB LDS = exactly 2 blocks/CU. Inner body unchanged.
//  blocks [0,256):   bp. b=blk>>5, pb=blk&31: owns 64 p; stages all 4096 y (2048 pairs).
//                    pg=tid&3 owns 16 p; s=tid>>2 in [0,128): 16 j-steps, stride 128.
//  blocks [256,512): bq. b=idx>>5, qb=idx&31: owns 128 q; stages all 2048 t (1024 pairs).
//                    pg=tid&7 owns 16 q; s=tid>>3 in [0,64): 16 j-steps, stride 64.
// Pair j in LDS: A[j]=(x0,x1,y0,y1), B[j]=(z0,z1,n0,n1), n = w^2-norm.
// Per 2 distances: 3 pk_fma + 1 min3 (owned norm deferred). Block -> 1 complete sum.
__global__ __launch_bounds__(512) void chamfer_main(const float* __restrict__ y,
                                                    const float* __restrict__ t,
                                                    const float* __restrict__ w,
                                                    float* __restrict__ blockSums)
{
    // A[2048] | B[2048] | quad[128] | scrB(512 f)  = 4352 f4 = 68 KB
    // scratch scr reuses A+B (16384 floats; max need 128*65=8320) - no quad overlap.
    __shared__ f4 lds4[4096 + 128 + 128];
    f4* quad = lds4 + 4096;
    float* scr  = (float*)lds4;
    float* scrB = (float*)(lds4 + 4096 + 128);   // 512 floats
    __shared__ float wsum[2];

    const int tid = threadIdx.x;
    const int blk = blockIdx.x;
    const float w0 = w[0]*w[0], w1 = w[1]*w[1], w2 = w[2]*w[2];

    int nOwn, nSlices, pg, s;
    f4* ldsA = lds4;
    f4* ldsB;

    if (blk < 256) {
        // ---- bp: own 64 p, stage 4096 y-points (2048 pairs) ----
        nOwn = 64; nSlices = 128; pg = tid & 3; s = tid >> 2;
        ldsB = lds4 + 2048;
        const int b = blk >> 5, pb = blk & 31;
        const float* yb = y + (size_t)b * 3 * NQ;
        const f2* xs = (const f2*)yb;
        const f2* ys = (const f2*)(yb + NQ);
        const f2* zs = (const f2*)(yb + 2*NQ);
        for (int i = tid; i < 2048; i += 512) {
            const f2 xp = xs[i], yp = ys[i], zp = zs[i];
            const float n0 = w0*xp.x*xp.x + w1*yp.x*yp.x + w2*zp.x*zp.x;
            const float n1 = w0*xp.y*xp.y + w1*yp.y*yp.y + w2*zp.y*zp.y;
            f4 va = {xp.x, xp.y, yp.x, yp.y};
            f4 vb = {zp.x, zp.y, n0, n1};
            ldsA[i] = va; ldsB[i] = vb;
        }
        if (tid < 64) {
            const float* tp = t + ((size_t)b * NP + pb*64 + tid) * 3;
            const float t0 = tp[0], t1 = tp[1], t2 = tp[2];
            f4 q = {-2.f*w0*t0, -2.f*w1*t1, -2.f*w2*t2,
                    w0*t0*t0 + w1*t1*t1 + w2*t2*t2};
            quad[tid] = q;
        }
    } else {
        // ---- bq: own 128 q, stage 2048 t-points (1024 pairs) ----
        nOwn = 128; nSlices = 64; pg = tid & 7; s = tid >> 3;
        ldsB = lds4 + 1024;
        const int idx = blk - 256;
        const int b = idx >> 5, qb = idx & 31;
        const float* tb = t + (size_t)b * NP * 3;
        for (int i = tid; i < 1024; i += 512) {
            const f2* tp2 = (const f2*)(tb + i*6);
            const f2 u0 = tp2[0], u1 = tp2[1], u2 = tp2[2];
            // pt0=(u0.x,u0.y,u1.x)  pt1=(u1.y,u2.x,u2.y)
            const float n0 = w0*u0.x*u0.x + w1*u0.y*u0.y + w2*u1.x*u1.x;
            const float n1 = w0*u1.y*u1.y + w1*u2.x*u2.x + w2*u2.y*u2.y;
            f4 va = {u0.x, u1.y, u0.y, u2.x};
            f4 vb = {u1.x, u2.y, n0, n1};
            ldsA[i] = va; ldsB[i] = vb;
        }
        if (tid < 128) {
            const float* yb = y + (size_t)b * 3 * NQ;
            const int q = qb*128 + tid;
            const float y0 = yb[q], y1 = yb[NQ+q], y2 = yb[2*NQ+q];
            f4 qv = {-2.f*w0*y0, -2.f*w1*y1, -2.f*w2*y2,
                     w0*y0*y0 + w1*y1*y1 + w2*y2*y2};
            quad[tid] = qv;
        }
    }
    __syncthreads();

    // hoist owned points into broadcast register pairs (R4-identical body)
    const int j0 = pg * 16;
    f2 qx[16], qy[16], qz[16];
    float mm[16];
    #pragma unroll
    for (int r = 0; r < 16; ++r) {
        const f4 qv = quad[j0 + r];
        f2 bx = {qv.x, qv.x}; qx[r] = bx;
        f2 by = {qv.y, qv.y}; qy[r] = by;
        f2 bz = {qv.z, qv.z}; qz[r] = bz;
        mm[r] = FINF;
    }

    // 16 interleaved pair-steps = 32 staged points per thread
    const f4* Ap = ldsA + s;
    const f4* Bp = ldsB + s;
    #pragma unroll 4
    for (int j = 0; j < 16; ++j) {
        const f4 a  = Ap[j * nSlices];
        const f4 bb = Bp[j * nSlices];
        const f2 vx = a.xy,  vy = a.zw;
        const f2 vz = bb.xy, vn = bb.zw;
        #pragma unroll
        for (int r = 0; r < 16; ++r) {
            f2 acc = pk_fma(qx[r], vx, vn);
            acc = pk_fma(qy[r], vy, acc);
            acc = pk_fma(qz[r], vz, acc);
            mm[r] = min3f(mm[r], acc.x, acc.y);
        }
    }
    __syncthreads();   // done reading ldsA/ldsB -> reuse as scratch

    // scr[j_own * (S+1) + s]  (padded stride, 2-way max)
    const int SP1 = nSlices + 1;
    #pragma unroll
    for (int r = 0; r < 16; ++r) scr[(j0 + r) * SP1 + s] = mm[r];
    __syncthreads();

    // stage 1: each thread folds 16 slices of one owned point
    {
        const int j  = tid & (nOwn - 1);
        const int s0 = tid / nOwn;              // [0, 512/nOwn)
        float v = FINF;
        #pragma unroll
        for (int k = 0; k < 16; ++k) v = fminf(v, scr[j * SP1 + s0*16 + k]);
        scrB[s0 * nOwn + j] = v;
    }
    __syncthreads();

    // stage 2: finish min, add deferred owned norm, sum owned points
    if (tid < nOwn) {
        const int nG = 512 / nOwn;              // bp: 8, bq: 4
        float v = scrB[tid];
        for (int g = 1; g < nG; ++g) v = fminf(v, scrB[g * nOwn + tid]);
        v += quad[tid].w;
        for (int off = 32; off > 0; off >>= 1) v += __shfl_down(v, off);
        if ((tid & 63) == 0) wsum[tid >> 6] = v;
    }
    __syncthreads();
    if (tid == 0) blockSums[blk] = (nOwn == 128) ? (wsum[0] + wsum[1]) : wsum[0];
}

// Final: single block, deterministic. bp sums in [0,256), bq sums in [256,512).
__global__ __launch_bounds__(256) void chamfer_final(const float* __restrict__ bs,
                                                     float* __restrict__ out)
{
    const int tid = threadIdx.x;
    double sv = (double)bs[tid] * (1.0 / (NB * NP))
              + (double)bs[256 + tid] * (1.0 / (NB * NQ));
    for (int off = 32; off > 0; off >>= 1) sv += __shfl_down(sv, off);
    __shared__ double redd[4];
    if ((tid & 63) == 0) redd[tid >> 6] = sv;
    __syncthreads();
    if (tid == 0) out[0] = (float)(redd[0] + redd[1] + redd[2] + redd[3]);
}

extern "C" void kernel_launch(void* const* d_in, const int* in_sizes, int n_in,
                              void* d_out, int out_size, void* d_ws, size_t ws_size,
                              hipStream_t stream) {
    const float* y = (const float*)d_in[0];   // [8,3,64,64]
    const float* t = (const float*)d_in[1];   // [8,2048,3]
    const float* w = (const float*)d_in[2];   // [3]
    float* out = (float*)d_out;
    float* blockSums = (float*)d_ws;          // 512 floats

    chamfer_main<<<512, 512, 0, stream>>>(y, t, w, blockSums);
    chamfer_final<<<1, 256, 0, stream>>>(blockSums, out);
}

// Round 12
// 20.380 us; speedup vs baseline: 1.2985x; 1.2985x over previous
//
#include <hip/hip_runtime.h>

#define NB 8
#define NQ 4096   // h*w
#define NP 2048
#define FINF 3.402823466e38f

typedef float f2 __attribute__((ext_vector_type(2)));
typedef float f4 __attribute__((ext_vector_type(4)));

// Session lesson ledger (each falsified by a measured regression):
//  R5: VOP3P needs 64-bit register pairs for ALL operands (scalar src0 won't assemble).
//  R6: __launch_bounds__ min-waves VGPR cap -> allocator remats LDS reads into the
//      inner loop (4.7x regression). Never cap VGPRs on this body.
//  R7/R10: shrinking tiles (1024-pair blocks) duplicates per-block fixed costs and
//      bq staging; loses 3-6 us despite 2x occupancy.
//  R8: per-thread __threadfence -> L2 writeback storm (+30 us).
//  R9: device-scope release/relaxed atomic finish -> ~13 ns per serialized RMW (+13 us).
//  R11: 512 threads/block at fixed tile doubles per-thread prologue device-wide (+6 us).
// Best measured: THIS kernel (20.45 us total).
__device__ __forceinline__ f2 pk_fma(f2 a, f2 b, f2 c) {
    f2 d;
    asm("v_pk_fma_f32 %0, %1, %2, %3" : "=v"(d) : "v"(a), "v"(b), "v"(c));
    return d;
}
__device__ __forceinline__ float min3f(float a, float b, float c) {
    float d;
    asm("v_min3_f32 %0, %1, %2, %3" : "=v"(d) : "v"(a), "v"(b), "v"(c));
    return d;
}

// 512 blocks x 256 threads, exactly 2 blocks/CU (66 KB LDS), uniform work.
//  blocks [0,256):   bp. b=blk>>5, pb=blk&31: owns 64 p; stages all 4096 y as 2048 pairs.
//  blocks [256,512): bq. b=idx>>5, qb=idx&31: owns 128 q; stages all 2048 t as 1024 pairs.
// Pair j in LDS: A[j]=(x0,x1,y0,y1), B[j]=(z0,z1,n0,n1) with n = w^2-norm of the point.
// Thread split: pg owns 16 points (f2 broadcast pairs in regs), s is the slice index.
// Slice access is INTERLEAVED (pair = j*nSlices + s) so a wave's lanes hit consecutive
// 16B LDS slots -> conflict-free ds_read_b128. Inner 2-distance step: 3 v_pk_fma_f32 +
// 1 v_min3_f32 (owned norm deferred to epilogue). Per block -> 1 float partial sum.
__global__ __launch_bounds__(256) void chamfer_main(const float* __restrict__ y,
                                                    const float* __restrict__ t,
                                                    const float* __restrict__ w,
                                                    float* __restrict__ blockSums)
{
    __shared__ f4 ldsA[2048];   // 32 KB
    __shared__ f4 ldsB[2048];   // 32 KB
    __shared__ f4 ldsQuad[128]; // owned: (-2w2c0, -2w2c1, -2w2c2, norm)
    __shared__ float wsum[2];

    const int tid = threadIdx.x;
    const int blk = blockIdx.x;
    const float w0 = w[0]*w[0], w1 = w[1]*w[1], w2 = w[2]*w[2];

    int nOwn, nSlices, pg, s;

    if (blk < 256) {
        // ---- bp: own 64 p, stage 4096 y-points (2048 pairs) ----
        nOwn = 64; nSlices = 64; pg = tid & 3; s = tid >> 2;
        const int b = blk >> 5, pb = blk & 31;
        const float* yb = y + (size_t)b * 3 * NQ;
        const f2* xs = (const f2*)yb;
        const f2* ys = (const f2*)(yb + NQ);
        const f2* zs = (const f2*)(yb + 2*NQ);
        for (int i = tid; i < 2048; i += 256) {
            const f2 xp = xs[i], yp = ys[i], zp = zs[i];
            const float n0 = w0*xp.x*xp.x + w1*yp.x*yp.x + w2*zp.x*zp.x;
            const float n1 = w0*xp.y*xp.y + w1*yp.y*yp.y + w2*zp.y*zp.y;
            f4 va = {xp.x, xp.y, yp.x, yp.y};
            f4 vb = {zp.x, zp.y, n0, n1};
            ldsA[i] = va; ldsB[i] = vb;
        }
        if (tid < 64) {
            const float* tp = t + ((size_t)b * NP + pb*64 + tid) * 3;
            const float t0 = tp[0], t1 = tp[1], t2 = tp[2];
            f4 q = {-2.f*w0*t0, -2.f*w1*t1, -2.f*w2*t2,
                    w0*t0*t0 + w1*t1*t1 + w2*t2*t2};
            ldsQuad[tid] = q;
        }
    } else {
        // ---- bq: own 128 q, stage 2048 t-points (1024 pairs) ----
        nOwn = 128; nSlices = 32; pg = tid & 7; s = tid >> 3;
        const int idx = blk - 256;
        const int b = idx >> 5, qb = idx & 31;
        const float* tb = t + (size_t)b * NP * 3;
        for (int i = tid; i < 1024; i += 256) {
            const f2* tp2 = (const f2*)(tb + i*6);
            const f2 u0 = tp2[0], u1 = tp2[1], u2 = tp2[2];
            // pt0=(u0.x,u0.y,u1.x)  pt1=(u1.y,u2.x,u2.y)
            const float n0 = w0*u0.x*u0.x + w1*u0.y*u0.y + w2*u1.x*u1.x;
            const float n1 = w0*u1.y*u1.y + w1*u2.x*u2.x + w2*u2.y*u2.y;
            f4 va = {u0.x, u1.y, u0.y, u2.x};
            f4 vb = {u1.x, u2.y, n0, n1};
            ldsA[i] = va; ldsB[i] = vb;
        }
        if (tid < 128) {
            const float* yb = y + (size_t)b * 3 * NQ;
            const int q = qb*128 + tid;
            const float y0 = yb[q], y1 = yb[NQ+q], y2 = yb[2*NQ+q];
            f4 qv = {-2.f*w0*y0, -2.f*w1*y1, -2.f*w2*y2,
                     w0*y0*y0 + w1*y1*y1 + w2*y2*y2};
            ldsQuad[tid] = qv;
        }
    }
    __syncthreads();

    // hoist owned points into broadcast register pairs
    const int j0 = pg * 16;
    f2 qx[16], qy[16], qz[16];
    float mm[16];
    #pragma unroll
    for (int r = 0; r < 16; ++r) {
        const f4 qv = ldsQuad[j0 + r];
        f2 bx = {qv.x, qv.x}; qx[r] = bx;
        f2 by = {qv.y, qv.y}; qy[r] = by;
        f2 bz = {qv.z, qv.z}; qz[r] = bz;
        mm[r] = FINF;
    }

    // 32 interleaved pair-steps = 64 staged points per thread
    const f4* Ap = ldsA + s;
    const f4* Bp = ldsB + s;
    #pragma unroll 4
    for (int j = 0; j < 32; ++j) {
        const f4 a  = Ap[j * nSlices];
        const f4 bb = Bp[j * nSlices];
        const f2 vx = a.xy,  vy = a.zw;
        const f2 vz = bb.xy, vn = bb.zw;
        #pragma unroll
        for (int r = 0; r < 16; ++r) {
            f2 acc = pk_fma(qx[r], vx, vn);
            acc = pk_fma(qy[r], vy, acc);
            acc = pk_fma(qz[r], vz, acc);
            mm[r] = min3f(mm[r], acc.x, acc.y);
        }
    }
    __syncthreads();   // done reading ldsA/ldsB -> reuse as scratch

    // scr[j_own * (S+1) + s]  (padded stride -> conflict-free)
    float* scr = (float*)ldsA;
    const int SP1 = nSlices + 1;
    #pragma unroll
    for (int r = 0; r < 16; ++r) scr[(j0 + r) * SP1 + s] = mm[r];
    __syncthreads();

    // stage 1: each thread folds 16 slices of one owned point
    float* scrB = (float*)ldsB;
    {
        const int j  = tid & (nOwn - 1);
        const int s0 = tid / nOwn;              // [0, 256/nOwn)
        float v = FINF;
        #pragma unroll
        for (int k = 0; k < 16; ++k) v = fminf(v, scr[j * SP1 + s0*16 + k]);
        scrB[s0 * nOwn + j] = v;
    }
    __syncthreads();

    // stage 2: finish min, add deferred owned norm, sum owned points
    if (tid < nOwn) {
        const int nG = 256 / nOwn;
        float v = scrB[tid];
        for (int g = 1; g < nG; ++g) v = fminf(v, scrB[g * nOwn + tid]);
        v += ldsQuad[tid].w;
        for (int off = 32; off > 0; off >>= 1) v += __shfl_down(v, off);
        if ((tid & 63) == 0) wsum[tid >> 6] = v;
    }
    __syncthreads();
    if (tid == 0) blockSums[blk] = (nOwn == 128) ? (wsum[0] + wsum[1]) : wsum[0];
}

// Final: single block, deterministic. bp sums in [0,256), bq sums in [256,512).
__global__ __launch_bounds__(256) void chamfer_final(const float* __restrict__ bs,
                                                     float* __restrict__ out)
{
    const int tid = threadIdx.x;
    double sv = (double)bs[tid] * (1.0 / (NB * NP))
              + (double)bs[256 + tid] * (1.0 / (NB * NQ));
    for (int off = 32; off > 0; off >>= 1) sv += __shfl_down(sv, off);
    __shared__ double redd[4];
    if ((tid & 63) == 0) redd[tid >> 6] = sv;
    __syncthreads();
    if (tid == 0) out[0] = (float)(redd[0] + redd[1] + redd[2] + redd[3]);
}

extern "C" void kernel_launch(void* const* d_in, const int* in_sizes, int n_in,
                              void* d_out, int out_size, void* d_ws, size_t ws_size,
                              hipStream_t stream) {
    const float* y = (const float*)d_in[0];   // [8,3,64,64]
    const float* t = (const float*)d_in[1];   // [8,2048,3]
    const float* w = (const float*)d_in[2];   // [3]
    float* out = (float*)d_out;
    float* blockSums = (float*)d_ws;          // 512 floats

    chamfer_main<<<512, 256, 0, stream>>>(y, t, w, blockSums);
    chamfer_final<<<1, 256, 0, stream>>>(blockSums, out);
}